// Round 10
// baseline (331.141 us; speedup 1.0000x reference)
//
#include <hip/hip_runtime.h>

#define LSEQ 1024

typedef __attribute__((ext_vector_type(8))) short bf16x8;
typedef __attribute__((ext_vector_type(4))) float f32x4;

__device__ __forceinline__ float gelu_f(float x){
    return 0.5f*x*(1.0f+erff(x*0.7071067811865476f));
}

__device__ __forceinline__ unsigned f2bf1(float x){
    unsigned u = __float_as_uint(x);
    return (u + 0x7fffu + ((u>>16)&1u)) >> 16;
}
__device__ __forceinline__ unsigned packbf(float lo, float hi){
    return f2bf1(lo) | (f2bf1(hi)<<16);
}

// ---------------------------------------------------------------------------
// pack_weights: all 5 weight matrices fp32 -> bf16 [m][k] contiguous.
// ---------------------------------------------------------------------------
__global__ __launch_bounds__(256) void pack_weights(
    const float* __restrict__ w0, const float* __restrict__ w1,
    const float* __restrict__ w2, const float* __restrict__ w3,
    const float* __restrict__ w4, unsigned short* __restrict__ dst)
{
    int idx4 = blockIdx.x*256 + threadIdx.x;
    const float* src; int off4;
    if(idx4 < 16384){ src=w0; off4=idx4; }
    else if(idx4 < 49152){ src=w1; off4=idx4-16384; }
    else if(idx4 < 65536){ src=w2; off4=idx4-49152; }
    else if(idx4 < 98304){ src=w3; off4=idx4-65536; }
    else { src=w4; off4=idx4-98304; }
    float4 v = ((const float4*)src)[off4];
    uint2 p; p.x = packbf(v.x,v.y); p.y = packbf(v.z,v.w);
    ((uint2*)dst)[idx4] = p;
}

// ---------------------------------------------------------------------------
// xform_bf16: dst[l][c] (bf16, l-major) = gelu( (src[c][l]-mu)*istd*gw+gb
//                                               [+ res[c][l]] )
// LDS-tiled 64c x 64l transpose; coalesced on both sides. grid (16, C/64, 8)
// ---------------------------------------------------------------------------
__global__ __launch_bounds__(256,2) void xform_bf16(
    const float* __restrict__ src, const float* __restrict__ res,
    const float* __restrict__ stats,
    const float* __restrict__ gw, const float* __restrict__ gb,
    float cnt_inv, int C, unsigned short* __restrict__ dst)
{
    __shared__ float T[64][68];
    int n = blockIdx.z;
    int ltile = blockIdx.x*64, ctile = blockIdx.y*64;
    int tid = threadIdx.x;

    float mu=0.f, istd=1.f;
    if(stats){
        float s1 = stats[2*n], s2 = stats[2*n+1];
        mu = s1*cnt_inv;
        istd = rsqrtf(s2*cnt_inv - mu*mu + 1e-5f);
    }
    const float* s = src + (size_t)n*C*LSEQ;
    const float* r = res ? res + (size_t)n*C*LSEQ : nullptr;

    int cl = tid>>4, l4 = (tid&15)*4;
    #pragma unroll
    for(int p=0;p<4;p++){
        int c_loc = p*16 + cl;
        int c = ctile + c_loc;
        float w_ = 1.f, b_ = 0.f;
        if(stats){ w_ = istd; b_ = -mu*istd; }
        if(gw){ b_ = gb[c] + b_*gw[c]; w_ *= gw[c]; }
        float4 v = *(const float4*)&s[(size_t)c*LSEQ + ltile + l4];
        float4 t;
        t.x = v.x*w_+b_; t.y = v.y*w_+b_; t.z = v.z*w_+b_; t.w = v.w*w_+b_;
        if(r){
            float4 rv = *(const float4*)&r[(size_t)c*LSEQ + ltile + l4];
            t.x += rv.x; t.y += rv.y; t.z += rv.z; t.w += rv.w;
        }
        t.x = gelu_f(t.x); t.y = gelu_f(t.y); t.z = gelu_f(t.z); t.w = gelu_f(t.w);
        *(float4*)&T[c_loc][l4] = t;
    }
    __syncthreads();

    int l_loc = tid>>2, cg = (tid&3)*16;
    uint4 o0, o1;
    o0.x = packbf(T[cg+0][l_loc],  T[cg+1][l_loc]);
    o0.y = packbf(T[cg+2][l_loc],  T[cg+3][l_loc]);
    o0.z = packbf(T[cg+4][l_loc],  T[cg+5][l_loc]);
    o0.w = packbf(T[cg+6][l_loc],  T[cg+7][l_loc]);
    o1.x = packbf(T[cg+8][l_loc],  T[cg+9][l_loc]);
    o1.y = packbf(T[cg+10][l_loc], T[cg+11][l_loc]);
    o1.z = packbf(T[cg+12][l_loc], T[cg+13][l_loc]);
    o1.w = packbf(T[cg+14][l_loc], T[cg+15][l_loc]);
    unsigned short* d = dst + (size_t)n*LSEQ*C + (size_t)(ltile+l_loc)*C + ctile + cg;
    *(uint4*)d = o0;
    *(uint4*)(d+8) = o1;
}

// ---------------------------------------------------------------------------
// gemm_bf16 v2: full-K LDS panels. C[n] = Abf (M,K [m][k]) x Bbf ([l][k]).
// Per 256-k half-panel: 16 dwordx4 loads in flight -> one barrier -> pure
// ds_read_b128 + MFMA stream (no per-chunk barriers; compiler emits
// fine-grained lgkmcnt). Row stride 264 shorts = 2-way bank alias (free).
// 64x64 tile; grid (16, M/64, 8). fp32 C + per-sample sum/sumsq stats.
// ---------------------------------------------------------------------------
__global__ __launch_bounds__(256,2) void gemm_bf16(
    const unsigned short* __restrict__ Abf,
    const unsigned short* __restrict__ Bbf,
    float* __restrict__ C,
    int M, int K,
    float* __restrict__ out_stats)
{
    __shared__ short As[64*264];   // 33.8 KB
    __shared__ short Bs[64*264];   // 33.8 KB

    int tid = threadIdx.x;
    int n = blockIdx.z, n0 = blockIdx.x*64, m0 = blockIdx.y*64;
    int wave = tid>>6, lane = tid&63;
    int col = lane&15, quad = lane>>4;
    int srow = tid>>2, sks = (tid&3)*8;

    const unsigned short* apt = Abf + (size_t)(m0+srow)*K + sks;
    const unsigned short* bpt = Bbf + ((size_t)n*LSEQ + n0+srow)*K + sks;

    f32x4 acc[4];
    #pragma unroll
    for(int t=0;t<4;t++) acc[t] = (f32x4){0.f,0.f,0.f,0.f};

    for(int kp=0; kp<K; kp+=256){
        __syncthreads();
        uint4 av[8], bw[8];
        #pragma unroll
        for(int i=0;i<8;i++) av[i] = *(const uint4*)(apt + kp + i*32);
        #pragma unroll
        for(int i=0;i<8;i++) bw[i] = *(const uint4*)(bpt + kp + i*32);
        #pragma unroll
        for(int i=0;i<8;i++) *(uint4*)&As[srow*264 + sks + i*32] = av[i];
        #pragma unroll
        for(int i=0;i<8;i++) *(uint4*)&Bs[srow*264 + sks + i*32] = bw[i];
        __syncthreads();

        #pragma unroll
        for(int kc=0;kc<8;kc++){
            bf16x8 af = *(bf16x8*)&As[(wave*16+col)*264 + kc*32 + quad*8];
            #pragma unroll
            for(int t=0;t<4;t++){
                bf16x8 bf = *(bf16x8*)&Bs[(t*16+col)*264 + kc*32 + quad*8];
                acc[t] = __builtin_amdgcn_mfma_f32_16x16x32_bf16(af, bf, acc[t], 0,0,0);
            }
        }
    }

    __syncthreads();
    size_t cbase = (size_t)n*M*LSEQ;
    float lsum=0.f, lsq=0.f;
    #pragma unroll
    for(int t=0;t<4;t++){
        #pragma unroll
        for(int r2=0;r2<4;r2++){
            int m = m0 + wave*16 + quad*4 + r2;
            int l = n0 + t*16 + col;
            float v = acc[t][r2];
            C[cbase + (size_t)m*LSEQ + l] = v;
            lsum += v; lsq += v*v;
        }
    }
    float* scr = (float*)As;
    scr[tid] = lsum; scr[256+tid] = lsq;
    __syncthreads();
    for(int s=128;s>0;s>>=1){
        if(tid<s){ scr[tid]+=scr[tid+s]; scr[256+tid]+=scr[256+tid+s]; }
        __syncthreads();
    }
    if(tid==0){
        atomicAdd(&out_stats[2*n],   scr[0]);
        atomicAdd(&out_stats[2*n+1], scr[256]);
    }
}

// ---------------------------------------------------------------------------
// head_cov / head_fin: analytic logit-LN istd via tr(Mk.Mq) (unchanged).
// ---------------------------------------------------------------------------
__global__ __launch_bounds__(256,2) void head_cov(
    const float* __restrict__ qkv,
    const float* __restrict__ s_qkv,
    const float* __restrict__ gq_w, const float* __restrict__ gq_b,
    float* __restrict__ covq, float* __restrict__ covk,
    float* __restrict__ sumq, float* __restrict__ sumk)
{
    __shared__ float Kq[16*132];
    __shared__ float Kk[16*132];
    int b = blockIdx.x;
    int head = b>>3, chunk = b&7;
    int n = head>>3, h = head&7;
    int tid = threadIdx.x;
    int m0 = chunk*128;

    float s1 = s_qkv[2*n], s2v = s_qkv[2*n+1];
    float mu  = s1*(1.f/524288.f);
    float var = s2v*(1.f/524288.f) - mu*mu;
    float istd = rsqrtf(var + 1e-5f);

    const float* base = qkv + (size_t)n*512*LSEQ;
    int m = tid&127, cg = tid>>7;
    #pragma unroll
    for(int cc=0;cc<8;cc++){
        int c = cg*8+cc;
        int chq = h*16+c, chk = 128+h*16+c;
        Kq[c*132+m] = (base[(size_t)chq*LSEQ+m0+m]-mu)*istd*gq_w[chq]+gq_b[chq];
        Kk[c*132+m] = (base[(size_t)chk*LSEQ+m0+m]-mu)*istd*gq_w[chk]+gq_b[chk];
    }
    __syncthreads();

    int i = tid>>4, j = tid&15;
    float q0=0,q1=0,q2=0,q3=0, k0=0,k1=0,k2=0,k3=0;
    for(int mm=0;mm<128;mm+=4){
        float4 qa = *(const float4*)&Kq[i*132+mm];
        float4 qb = *(const float4*)&Kq[j*132+mm];
        q0 += qa.x*qb.x; q1 += qa.y*qb.y; q2 += qa.z*qb.z; q3 += qa.w*qb.w;
        float4 ka = *(const float4*)&Kk[i*132+mm];
        float4 kb = *(const float4*)&Kk[j*132+mm];
        k0 += ka.x*kb.x; k1 += ka.y*kb.y; k2 += ka.z*kb.z; k3 += ka.w*kb.w;
    }
    atomicAdd(&covq[head*256 + i*16 + j], (q0+q1)+(q2+q3));
    atomicAdd(&covk[head*256 + i*16 + j], (k0+k1)+(k2+k3));

    if(i==0){
        float s=0.f;
        for(int mm=0;mm<128;mm+=4){
            float4 v = *(const float4*)&Kq[j*132+mm];
            s += (v.x+v.y)+(v.z+v.w);
        }
        atomicAdd(&sumq[head*16+j], s);
    }
    if(i==1){
        float s=0.f;
        for(int mm=0;mm<128;mm+=4){
            float4 v = *(const float4*)&Kk[j*132+mm];
            s += (v.x+v.y)+(v.z+v.w);
        }
        atomicAdd(&sumk[head*16+j], s);
    }
}

__global__ __launch_bounds__(256) void head_fin(
    const float* __restrict__ covq, const float* __restrict__ covk,
    const float* __restrict__ sumq, const float* __restrict__ sumk,
    float* __restrict__ istd_head)
{
    int tid = threadIdx.x;
    int head = tid>>2, part = tid&3;
    double S2 = 0.0;
    #pragma unroll 8
    for(int e=part*64; e<part*64+64; e++)
        S2 += (double)covq[head*256+e]*(double)covk[head*256+e];
    S2 += __shfl_xor(S2,1);
    S2 += __shfl_xor(S2,2);
    if(part==0){
        double S1 = 0.0;
        for(int c=0;c<16;c++) S1 += (double)sumq[head*16+c]*(double)sumk[head*16+c];
        double cnt = 1048576.0;
        double mean = S1/cnt;
        double v2 = S2/cnt - mean*mean;
        if(v2 < 0.0) v2 = 0.0;
        istd_head[head] = (float)(1.0/sqrt(v2 + 1e-5));
    }
}

// ---------------------------------------------------------------------------
// Attention v6: MFMA flash attention, 64-row blocks (1024 blocks, 3/CU by
// LDS ~44KB, 12 waves/CU vs v5's 8). XCD swizzle kept: head = b&63 so all
// row-blocks of a head share an XCD (K/V L2-resident; v5 measured 8.3MB
// fetch vs 65MB unswizzled). Each wave owns one 16-row Q tile.
// ---------------------------------------------------------------------------
__global__ __launch_bounds__(256) void attn_kernel(
    const float* __restrict__ qkv,
    const float* __restrict__ s_qkv,
    const float* __restrict__ gq_w, const float* __restrict__ gq_b,
    const float* __restrict__ istd_head,
    float* __restrict__ out,
    float* __restrict__ out_stats)
{
    __shared__ short Qs[64*40];     // [row][c], c 0..15 real, 16..31 zero
    __shared__ short Ks[128*40];    // [m][c], same padding
    __shared__ short Vs[32*136];    // [d][m]
    __shared__ short Ps[64*152];    // [row][m] bf16 P
    __shared__ float bounds_l[64];
    __shared__ float issum_l[64];
    __shared__ float sred4[4];

    int b = blockIdx.x;
    int head = b&63, rb = b>>6;     // rb 0..15, 64-row chunks
    int n = head>>3, h = head&7;
    int tid = threadIdx.x;
    int wv = tid>>6, lane = tid&63;
    int col = lane&15, quad = lane>>4;
    int l0 = rb*64;

    const float* base = qkv + (size_t)n*512*LSEQ;
    float s1 = s_qkv[2*n], s2v = s_qkv[2*n+1];
    float mu  = s1*(1.f/524288.f);
    float var = s2v*(1.f/524288.f) - mu*mu;
    float istd = rsqrtf(var + 1e-5f);
    float ih = istd_head[head];

    // zero the k-pad of Qs (64 rows) and Ks (128 rows)
    {
        uint4 z = {0,0,0,0};
        if(tid < 128){
            int row = tid>>1, hf = tid&1;
            *(uint4*)&Qs[row*40 + 16 + hf*8] = z;
        }
        int row = tid>>1, hf = tid&1;
        *(uint4*)&Ks[row*40 + 16 + hf*8] = z;
    }

    // stage Q (64 rows x 16c, 4c per thread) + per-row norms
    {
        int row = tid>>2, cg = tid&3;
        float qn2p = 0.f;
        float qv[4];
        #pragma unroll
        for(int cc=0;cc<4;cc++){
            int ch = h*16 + cg*4 + cc;
            float w_ = gq_w[ch]*istd, b_ = gq_b[ch]-mu*istd*gq_w[ch];
            float x = base[(size_t)ch*LSEQ + l0 + row];
            float v = x*w_ + b_;
            qv[cc] = v;
            qn2p += v*v;
        }
        uint2 pq;
        pq.x = packbf(qv[0],qv[1]); pq.y = packbf(qv[2],qv[3]);
        *(uint2*)&Qs[row*40 + cg*4] = pq;
        qn2p += __shfl_xor(qn2p, 1);
        qn2p += __shfl_xor(qn2p, 2);
        if(cg==0) bounds_l[row] = sqrtf(qn2p);
    }

    // K max-norm over all 1024 m (Cauchy-Schwarz bound)
    {
        float kn2max = 0.f;
        #pragma unroll
        for(int j=0;j<4;j++){
            int m = tid + j*256;
            float s = 0.f;
            for(int c=0;c<16;c++){
                int ch = 128+h*16+c;
                float x = base[(size_t)ch*LSEQ + m];
                float kv = (x-mu)*istd*gq_w[ch]+gq_b[ch];
                s += kv*kv;
            }
            kn2max = fmaxf(kn2max, s);
        }
        #pragma unroll
        for(int d=1;d<64;d<<=1) kn2max = fmaxf(kn2max, __shfl_xor(kn2max,d));
        if(lane==0) sred4[wv] = kn2max;
    }
    __syncthreads();
    float kmax = sqrtf(fmaxf(fmaxf(sred4[0],sred4[1]),fmaxf(sred4[2],sred4[3])));

    // this wave's Q tile (16 rows)
    int rl = wv*16 + col;
    bf16x8 qf = *(bf16x8*)&Qs[rl*40 + quad*8];
    float B2 = bounds_l[rl]*kmax*ih;
    int grow = l0 + rl;

    int km_l = tid>>1, kg = tid&1;
    float kw8[8], kb8[8];
    #pragma unroll
    for(int cc=0;cc<8;cc++){
        int ch = 128+h*16+kg*8+cc;
        kw8[cc] = gq_w[ch]*istd;
        kb8[cc] = gq_b[ch]-mu*istd*gq_w[ch];
    }
    int vd = tid>>3, vmg = tid&7;
    float vw, vb;
    {
        int ch = 256+h*32+vd;
        vw = gq_w[ch]*istd;
        vb = gq_b[ch]-mu*istd*gq_w[ch];
    }
    const float* kp = base + (size_t)(128+h*16+kg*8)*LSEQ + km_l;
    const float* vp = base + (size_t)(256+h*32+vd)*LSEQ + vmg*16;

    f32x4 acc[2];
    acc[0]=(f32x4){0,0,0,0}; acc[1]=(f32x4){0,0,0,0};
    float ssum = 0.f;
    const f32x4 zero4 = {0.f,0.f,0.f,0.f};

    for(int mc=0;mc<8;mc++){
        int M0 = mc*128;
        {
            float kv[8];
            #pragma unroll
            for(int cc=0;cc<8;cc++)
                kv[cc] = kp[(size_t)cc*LSEQ + M0]*kw8[cc] + kb8[cc];
            uint4 pk;
            pk.x=packbf(kv[0],kv[1]); pk.y=packbf(kv[2],kv[3]);
            pk.z=packbf(kv[4],kv[5]); pk.w=packbf(kv[6],kv[7]);
            *(uint4*)&Ks[km_l*40 + kg*8] = pk;
        }
        {
            float4 x0 = *(const float4*)&vp[M0];
            float4 x1 = *(const float4*)&vp[M0+4];
            float4 x2 = *(const float4*)&vp[M0+8];
            float4 x3 = *(const float4*)&vp[M0+12];
            uint4 p0, p1;
            p0.x = packbf(x0.x*vw+vb, x0.y*vw+vb);
            p0.y = packbf(x0.z*vw+vb, x0.w*vw+vb);
            p0.z = packbf(x1.x*vw+vb, x1.y*vw+vb);
            p0.w = packbf(x1.z*vw+vb, x1.w*vw+vb);
            p1.x = packbf(x2.x*vw+vb, x2.y*vw+vb);
            p1.y = packbf(x2.z*vw+vb, x2.w*vw+vb);
            p1.z = packbf(x3.x*vw+vb, x3.y*vw+vb);
            p1.w = packbf(x3.z*vw+vb, x3.w*vw+vb);
            *(uint4*)&Vs[vd*136 + vmg*16]     = p0;
            *(uint4*)&Vs[vd*136 + vmg*16 + 8] = p1;
        }
        __syncthreads();

        // S^T = K.Q^T -> exp -> P (wave-local rows)
        #pragma unroll
        for(int mt=0;mt<8;mt++){
            bf16x8 ak = *(bf16x8*)&Ks[(mt*16+col)*40 + quad*8];
            f32x4 sc = __builtin_amdgcn_mfma_f32_16x16x32_bf16(ak, qf, zero4, 0,0,0);
            int mbase = M0 + mt*16 + quad*4;
            float pr[4];
            #pragma unroll
            for(int r=0;r<4;r++){
                float e = __expf(fmaf(sc[r], ih, -B2));
                pr[r] = (mbase + r == grow) ? 0.f : e;
                ssum += pr[r];
            }
            uint2 pw;
            pw.x = packbf(pr[0],pr[1]); pw.y = packbf(pr[2],pr[3]);
            *(uint2*)&Ps[rl*152 + mt*16 + quad*4] = pw;
        }
        // PV: out += P.V
        #pragma unroll
        for(int kk=0;kk<4;kk++){
            bf16x8 bv0 = *(bf16x8*)&Vs[( col)*136 + kk*32 + quad*8];
            bf16x8 bv1 = *(bf16x8*)&Vs[(16+col)*136 + kk*32 + quad*8];
            bf16x8 ap = *(bf16x8*)&Ps[rl*152 + kk*32 + quad*8];
            acc[0] = __builtin_amdgcn_mfma_f32_16x16x32_bf16(ap, bv0, acc[0], 0,0,0);
            acc[1] = __builtin_amdgcn_mfma_f32_16x16x32_bf16(ap, bv1, acc[1], 0,0,0);
        }
        __syncthreads();
    }

    // row sums -> inverse
    {
        float v = ssum;
        v += __shfl_xor(v,16);
        v += __shfl_xor(v,32);
        if(quad==0) issum_l[rl] = v;
    }
    __syncthreads();
    if(tid<64) issum_l[tid] = 1.f/issum_l[tid];
    __syncthreads();

    // restage output fp32 [d][row] for coalesced global write
    float* ep = (float*)Ps;   // 32*68*4B = 8.7KB < Ps
    #pragma unroll
    for(int dt=0;dt<2;dt++)
        *(f32x4*)&ep[(dt*16+col)*68 + wv*16 + quad*4] = acc[dt];
    __syncthreads();

    float lsum=0.f, lsq=0.f;
    size_t obase = (size_t)n*262144 + (size_t)h*32*LSEQ + l0;
    #pragma unroll
    for(int t=0;t<8;t++){
        int idx = t*256 + tid;
        int d = idx>>6, row = idx&63;
        float y = ep[d*68+row]*issum_l[row];
        out[obase + (size_t)d*LSEQ + row] = y;
        lsum += y; lsq += y*y;
    }
    float* red = (float*)Ks;
    red[tid]=lsum; red[256+tid]=lsq;
    __syncthreads();
    for(int s=128;s>0;s>>=1){
        if(tid<s){ red[tid]+=red[tid+s]; red[256+tid]+=red[256+tid+s]; }
        __syncthreads();
    }
    if(tid==0){
        atomicAdd(&out_stats[2*n],   red[0]);
        atomicAdd(&out_stats[2*n+1], red[256]);
    }
}

// ---------------------------------------------------------------------------
// ew_final: out = gelu( f1 + gn_g2(h2) ), f1 = gelu(f + gn_go(x)) recomputed.
// ---------------------------------------------------------------------------
__global__ __launch_bounds__(256) void ew_final(
    const float* __restrict__ f, const float* __restrict__ x,
    const float* __restrict__ h2,
    const float* __restrict__ sx, const float* __restrict__ sh,
    const float* __restrict__ go_w, const float* __restrict__ go_b,
    const float* __restrict__ g2_w, const float* __restrict__ g2_b,
    float* __restrict__ out)
{
    int idx = blockIdx.x*256 + threadIdx.x;
    int n = idx >> 16;
    int c = (idx >> 8) & 255;
    float mux, isx, muh, ish;
    {
        float s1 = sx[2*n], s2 = sx[2*n+1];
        mux = s1*(1.f/262144.f);
        isx = rsqrtf(s2*(1.f/262144.f) - mux*mux + 1e-5f);
        float t1 = sh[2*n], t2 = sh[2*n+1];
        muh = t1*(1.f/262144.f);
        ish = rsqrtf(t2*(1.f/262144.f) - muh*muh + 1e-5f);
    }
    float wo = go_w[c]*isx, bo = go_b[c]-mux*isx*go_w[c];
    float w2 = g2_w[c]*ish, b2 = g2_b[c]-muh*ish*g2_w[c];
    float4 xv = ((const float4*)x)[idx];
    float4 fv = ((const float4*)f)[idx];
    float4 hv = ((const float4*)h2)[idx];
    float4 ov;
    float f1;
    f1 = gelu_f(fv.x + xv.x*wo+bo); ov.x = gelu_f(f1 + hv.x*w2+b2);
    f1 = gelu_f(fv.y + xv.y*wo+bo); ov.y = gelu_f(f1 + hv.y*w2+b2);
    f1 = gelu_f(fv.z + xv.z*wo+bo); ov.z = gelu_f(f1 + hv.z*w2+b2);
    f1 = gelu_f(fv.w + xv.w*wo+bo); ov.w = gelu_f(f1 + hv.w*w2+b2);
    ((float4*)out)[idx] = ov;
}

// ---------------------------------------------------------------------------
extern "C" void kernel_launch(void* const* d_in, const int* in_sizes, int n_in,
                              void* d_out, int out_size, void* d_ws, size_t ws_size,
                              hipStream_t stream) {
    const float* f     = (const float*)d_in[0];
    const float* w_z   = (const float*)d_in[1];
    const float* gz_w  = (const float*)d_in[2];
    const float* gz_b  = (const float*)d_in[3];
    const float* w_qkv = (const float*)d_in[4];
    const float* gq_w  = (const float*)d_in[5];
    const float* gq_b  = (const float*)d_in[6];
    const float* w_out = (const float*)d_in[7];
    const float* go_w  = (const float*)d_in[8];
    const float* go_b  = (const float*)d_in[9];
    const float* w_f1  = (const float*)d_in[10];
    const float* g1_w  = (const float*)d_in[11];
    const float* g1_b  = (const float*)d_in[12];
    const float* w_f2  = (const float*)d_in[13];
    const float* g2_w  = (const float*)d_in[14];
    const float* g2_b  = (const float*)d_in[15];

    float* ws = (float*)d_ws;
    float* stats = ws;
    float* s_z    = stats + 0;
    float* s_qkv  = stats + 16;
    float* s_attn = stats + 32;
    float* s_x    = stats + 48;
    float* s_h1   = stats + 64;
    float* s_h2   = stats + 80;
    float* istdh  = stats + 96;

    float* qkvF = ws + 256;            // 4M floats: qkv -> h1 -> h2
    float* z0F  = qkvF + 4194304;      // 2M floats: z0 -> attn_out -> t4(bf16)
    float* xF   = z0F + 2097152;       // 2M floats: covs -> x (persists)
    unsigned short* t0 = (unsigned short*)(xF + 2097152);  // t0 -> t2
    unsigned short* t1 = t0 + 2097152;                     // t1 -> t3
    unsigned short* wp = t1 + 2097152;
    unsigned short* t4 = (unsigned short*)z0F;
    unsigned short* wp_z   = wp;
    unsigned short* wp_qkv = wp + 65536;
    unsigned short* wp_out = wp + 196608;
    unsigned short* wp_f1  = wp + 262144;
    unsigned short* wp_f2  = wp + 393216;

    float* covq = xF;
    float* covk = xF + 16384;
    float* sumq = xF + 32768;
    float* sumk = xF + 33792;

    float* outp = (float*)d_out;

    hipMemsetAsync(stats, 0, 256*sizeof(float), stream);
    hipMemsetAsync(covq, 0, 34816*sizeof(float), stream);

    dim3 blk(256);
    pack_weights<<<512,blk,0,stream>>>(w_z, w_qkv, w_out, w_f1, w_f2, wp);
    // t0 = bf16[gelu(f)]
    xform_bf16<<<dim3(16,4,8),blk,0,stream>>>(f, nullptr, nullptr, nullptr, nullptr,
        0.f, 256, t0);
    // z0 = w_z @ t0
    gemm_bf16<<<dim3(16,4,8),blk,0,stream>>>(wp_z, t0, z0F, 256, 256, s_z);
    // t1 = bf16[gelu(gn_gz(z0))]
    xform_bf16<<<dim3(16,4,8),blk,0,stream>>>(z0F, nullptr, s_z, gz_w, gz_b,
        1.f/262144.f, 256, t1);
    // qkv = w_qkv @ t1
    gemm_bf16<<<dim3(16,8,8),blk,0,stream>>>(wp_qkv, t1, qkvF, 512, 256, s_qkv);
    // analytic logit-LN istd
    head_cov<<<512,blk,0,stream>>>(qkvF, s_qkv, gq_w, gq_b, covq, covk, sumq, sumk);
    head_fin<<<1,blk,0,stream>>>(covq, covk, sumq, sumk, istdh);
    // attention -> attn_out (z0F region)
    attn_kernel<<<1024,blk,0,stream>>>(qkvF, s_qkv, gq_w, gq_b, istdh, z0F, s_attn);
    // t2 = bf16[gelu(ln(attn_out))]
    xform_bf16<<<dim3(16,4,8),blk,0,stream>>>(z0F, nullptr, s_attn, nullptr, nullptr,
        1.f/262144.f, 256, t0);
    // x = w_out @ t2
    gemm_bf16<<<dim3(16,4,8),blk,0,stream>>>(wp_out, t0, xF, 256, 256, s_x);
    // t3 = bf16[gelu(f + gn_go(x))]
    xform_bf16<<<dim3(16,4,8),blk,0,stream>>>(xF, f, s_x, go_w, go_b,
        1.f/262144.f, 256, t1);
    // h1 = w_f1 @ t3
    gemm_bf16<<<dim3(16,8,8),blk,0,stream>>>(wp_f1, t1, qkvF, 512, 256, s_h1);
    // t4 = bf16[gelu(gn_g1(h1))]
    xform_bf16<<<dim3(16,8,8),blk,0,stream>>>(qkvF, nullptr, s_h1, g1_w, g1_b,
        1.f/524288.f, 512, t4);
    // h2 = w_f2 @ t4
    gemm_bf16<<<dim3(16,4,8),blk,0,stream>>>(wp_f2, t4, qkvF, 256, 512, s_h2);
    // out = gelu( gelu(f + gn_go(x)) + gn_g2(h2) )
    ew_final<<<2048,blk,0,stream>>>(f, xF, qkvF, s_x, s_h2,
        go_w, go_b, g2_w, g2_b, outp);
}

// Round 11
// 300.094 us; speedup vs baseline: 1.1035x; 1.1035x over previous
//
#include <hip/hip_runtime.h>

#define LSEQ 1024

typedef __attribute__((ext_vector_type(8))) short bf16x8;
typedef __attribute__((ext_vector_type(4))) float f32x4;

__device__ __forceinline__ float gelu_f(float x){
    return 0.5f*x*(1.0f+erff(x*0.7071067811865476f));
}

__device__ __forceinline__ unsigned f2bf1(float x){
    unsigned u = __float_as_uint(x);
    return (u + 0x7fffu + ((u>>16)&1u)) >> 16;
}
__device__ __forceinline__ unsigned packbf(float lo, float hi){
    return f2bf1(lo) | (f2bf1(hi)<<16);
}

// ---------------------------------------------------------------------------
// prologue: one kernel replacing pack_weights + xform_t0 + 2 memsets
// (4 dispatches -> 1; the pipeline is a pure serial chain, so each removed
// dispatch removes a launch+drain gap).
//   b <  512 : xform of f -> t0 (bf16 l-major, gelu, C=256)
//   b < 1024 : pack 5 weight matrices fp32 -> bf16 [m][k]
//   b = 1024 : zero stats (256 floats)
//   b > 1024 : zero cov scratch (34816 floats, 34 blocks)
// ---------------------------------------------------------------------------
__global__ __launch_bounds__(256,2) void prologue(
    const float* __restrict__ w0, const float* __restrict__ w1,
    const float* __restrict__ w2, const float* __restrict__ w3,
    const float* __restrict__ w4, unsigned short* __restrict__ wdst,
    const float* __restrict__ f, unsigned short* __restrict__ t0,
    float* __restrict__ stats, float* __restrict__ covs)
{
    __shared__ float T[64][68];
    int b = blockIdx.x;
    int tid = threadIdx.x;

    if(b < 512){
        // ---- xform_t0: dst[l][c] = gelu(f[c][l]) ----
        int ltile = (b&15)*64, ctile = ((b>>4)&3)*64, n = b>>6;
        const float* s = f + (size_t)n*256*LSEQ;
        int cl = tid>>4, l4 = (tid&15)*4;
        #pragma unroll
        for(int p=0;p<4;p++){
            int c_loc = p*16 + cl;
            float4 v = *(const float4*)&s[(size_t)(ctile+c_loc)*LSEQ + ltile + l4];
            float4 t;
            t.x = gelu_f(v.x); t.y = gelu_f(v.y); t.z = gelu_f(v.z); t.w = gelu_f(v.w);
            *(float4*)&T[c_loc][l4] = t;
        }
        __syncthreads();
        int l_loc = tid>>2, cg = (tid&3)*16;
        uint4 o0, o1;
        o0.x = packbf(T[cg+0][l_loc],  T[cg+1][l_loc]);
        o0.y = packbf(T[cg+2][l_loc],  T[cg+3][l_loc]);
        o0.z = packbf(T[cg+4][l_loc],  T[cg+5][l_loc]);
        o0.w = packbf(T[cg+6][l_loc],  T[cg+7][l_loc]);
        o1.x = packbf(T[cg+8][l_loc],  T[cg+9][l_loc]);
        o1.y = packbf(T[cg+10][l_loc], T[cg+11][l_loc]);
        o1.z = packbf(T[cg+12][l_loc], T[cg+13][l_loc]);
        o1.w = packbf(T[cg+14][l_loc], T[cg+15][l_loc]);
        unsigned short* d = t0 + (size_t)n*LSEQ*256 + (size_t)(ltile+l_loc)*256 + ctile + cg;
        *(uint4*)d = o0;
        *(uint4*)(d+8) = o1;
    } else if(b < 1024){
        // ---- pack weights ----
        int idx4 = (b-512)*256 + tid;
        const float* src; int off4;
        if(idx4 < 16384){ src=w0; off4=idx4; }
        else if(idx4 < 49152){ src=w1; off4=idx4-16384; }
        else if(idx4 < 65536){ src=w2; off4=idx4-49152; }
        else if(idx4 < 98304){ src=w3; off4=idx4-65536; }
        else { src=w4; off4=idx4-98304; }
        float4 v = ((const float4*)src)[off4];
        uint2 p; p.x = packbf(v.x,v.y); p.y = packbf(v.z,v.w);
        ((uint2*)wdst)[idx4] = p;
    } else if(b == 1024){
        if(tid < 64) ((float4*)stats)[tid] = (float4){0.f,0.f,0.f,0.f};
    } else {
        int i = (b-1025)*256 + tid;   // 34 blocks x 256 = 8704 f4 = 34816 floats
        ((float4*)covs)[i] = (float4){0.f,0.f,0.f,0.f};
    }
}

// ---------------------------------------------------------------------------
// xform_bf16: dst[l][c] (bf16, l-major) = gelu( (src[c][l]-mu)*istd*gw+gb
//                                               [+ res[c][l]] )
// LDS-tiled 64c x 64l transpose; coalesced on both sides. grid (16, C/64, 8)
// ---------------------------------------------------------------------------
__global__ __launch_bounds__(256,2) void xform_bf16(
    const float* __restrict__ src, const float* __restrict__ res,
    const float* __restrict__ stats,
    const float* __restrict__ gw, const float* __restrict__ gb,
    float cnt_inv, int C, unsigned short* __restrict__ dst)
{
    __shared__ float T[64][68];
    int n = blockIdx.z;
    int ltile = blockIdx.x*64, ctile = blockIdx.y*64;
    int tid = threadIdx.x;

    float mu=0.f, istd=1.f;
    if(stats){
        float s1 = stats[2*n], s2 = stats[2*n+1];
        mu = s1*cnt_inv;
        istd = rsqrtf(s2*cnt_inv - mu*mu + 1e-5f);
    }
    const float* s = src + (size_t)n*C*LSEQ;
    const float* r = res ? res + (size_t)n*C*LSEQ : nullptr;

    int cl = tid>>4, l4 = (tid&15)*4;
    #pragma unroll
    for(int p=0;p<4;p++){
        int c_loc = p*16 + cl;
        int c = ctile + c_loc;
        float w_ = 1.f, b_ = 0.f;
        if(stats){ w_ = istd; b_ = -mu*istd; }
        if(gw){ b_ = gb[c] + b_*gw[c]; w_ *= gw[c]; }
        float4 v = *(const float4*)&s[(size_t)c*LSEQ + ltile + l4];
        float4 t;
        t.x = v.x*w_+b_; t.y = v.y*w_+b_; t.z = v.z*w_+b_; t.w = v.w*w_+b_;
        if(r){
            float4 rv = *(const float4*)&r[(size_t)c*LSEQ + ltile + l4];
            t.x += rv.x; t.y += rv.y; t.z += rv.z; t.w += rv.w;
        }
        t.x = gelu_f(t.x); t.y = gelu_f(t.y); t.z = gelu_f(t.z); t.w = gelu_f(t.w);
        *(float4*)&T[c_loc][l4] = t;
    }
    __syncthreads();

    int l_loc = tid>>2, cg = (tid&3)*16;
    uint4 o0, o1;
    o0.x = packbf(T[cg+0][l_loc],  T[cg+1][l_loc]);
    o0.y = packbf(T[cg+2][l_loc],  T[cg+3][l_loc]);
    o0.z = packbf(T[cg+4][l_loc],  T[cg+5][l_loc]);
    o0.w = packbf(T[cg+6][l_loc],  T[cg+7][l_loc]);
    o1.x = packbf(T[cg+8][l_loc],  T[cg+9][l_loc]);
    o1.y = packbf(T[cg+10][l_loc], T[cg+11][l_loc]);
    o1.z = packbf(T[cg+12][l_loc], T[cg+13][l_loc]);
    o1.w = packbf(T[cg+14][l_loc], T[cg+15][l_loc]);
    unsigned short* d = dst + (size_t)n*LSEQ*C + (size_t)(ltile+l_loc)*C + ctile + cg;
    *(uint4*)d = o0;
    *(uint4*)(d+8) = o1;
}

// ---------------------------------------------------------------------------
// gemm_bf16 (R10 full-K panels, kept): C[n] = Abf (M,K [m][k]) x Bbf ([l][k]).
// ---------------------------------------------------------------------------
__global__ __launch_bounds__(256,2) void gemm_bf16(
    const unsigned short* __restrict__ Abf,
    const unsigned short* __restrict__ Bbf,
    float* __restrict__ C,
    int M, int K,
    float* __restrict__ out_stats)
{
    __shared__ short As[64*264];
    __shared__ short Bs[64*264];

    int tid = threadIdx.x;
    int n = blockIdx.z, n0 = blockIdx.x*64, m0 = blockIdx.y*64;
    int wave = tid>>6, lane = tid&63;
    int col = lane&15, quad = lane>>4;
    int srow = tid>>2, sks = (tid&3)*8;

    const unsigned short* apt = Abf + (size_t)(m0+srow)*K + sks;
    const unsigned short* bpt = Bbf + ((size_t)n*LSEQ + n0+srow)*K + sks;

    f32x4 acc[4];
    #pragma unroll
    for(int t=0;t<4;t++) acc[t] = (f32x4){0.f,0.f,0.f,0.f};

    for(int kp=0; kp<K; kp+=256){
        __syncthreads();
        uint4 av[8], bw[8];
        #pragma unroll
        for(int i=0;i<8;i++) av[i] = *(const uint4*)(apt + kp + i*32);
        #pragma unroll
        for(int i=0;i<8;i++) bw[i] = *(const uint4*)(bpt + kp + i*32);
        #pragma unroll
        for(int i=0;i<8;i++) *(uint4*)&As[srow*264 + sks + i*32] = av[i];
        #pragma unroll
        for(int i=0;i<8;i++) *(uint4*)&Bs[srow*264 + sks + i*32] = bw[i];
        __syncthreads();

        #pragma unroll
        for(int kc=0;kc<8;kc++){
            bf16x8 af = *(bf16x8*)&As[(wave*16+col)*264 + kc*32 + quad*8];
            #pragma unroll
            for(int t=0;t<4;t++){
                bf16x8 bf = *(bf16x8*)&Bs[(t*16+col)*264 + kc*32 + quad*8];
                acc[t] = __builtin_amdgcn_mfma_f32_16x16x32_bf16(af, bf, acc[t], 0,0,0);
            }
        }
    }

    __syncthreads();
    size_t cbase = (size_t)n*M*LSEQ;
    float lsum=0.f, lsq=0.f;
    #pragma unroll
    for(int t=0;t<4;t++){
        #pragma unroll
        for(int r2=0;r2<4;r2++){
            int m = m0 + wave*16 + quad*4 + r2;
            int l = n0 + t*16 + col;
            float v = acc[t][r2];
            C[cbase + (size_t)m*LSEQ + l] = v;
            lsum += v; lsq += v*v;
        }
    }
    float* scr = (float*)As;
    scr[tid] = lsum; scr[256+tid] = lsq;
    __syncthreads();
    for(int s=128;s>0;s>>=1){
        if(tid<s){ scr[tid]+=scr[tid+s]; scr[256+tid]+=scr[256+tid+s]; }
        __syncthreads();
    }
    if(tid==0){
        atomicAdd(&out_stats[2*n],   scr[0]);
        atomicAdd(&out_stats[2*n+1], scr[256]);
    }
}

// ---------------------------------------------------------------------------
// head_cov: partial 16x16 covariances of normalized q,k + per-channel sums.
// S2 of the LxL logit map = tr(Mk.Mq) (head_fin is folded into attn).
// ---------------------------------------------------------------------------
__global__ __launch_bounds__(256,2) void head_cov(
    const float* __restrict__ qkv,
    const float* __restrict__ s_qkv,
    const float* __restrict__ gq_w, const float* __restrict__ gq_b,
    float* __restrict__ covq, float* __restrict__ covk,
    float* __restrict__ sumq, float* __restrict__ sumk)
{
    __shared__ float Kq[16*132];
    __shared__ float Kk[16*132];
    int b = blockIdx.x;
    int head = b>>3, chunk = b&7;
    int n = head>>3, h = head&7;
    int tid = threadIdx.x;
    int m0 = chunk*128;

    float s1 = s_qkv[2*n], s2v = s_qkv[2*n+1];
    float mu  = s1*(1.f/524288.f);
    float var = s2v*(1.f/524288.f) - mu*mu;
    float istd = rsqrtf(var + 1e-5f);

    const float* base = qkv + (size_t)n*512*LSEQ;
    int m = tid&127, cg = tid>>7;
    #pragma unroll
    for(int cc=0;cc<8;cc++){
        int c = cg*8+cc;
        int chq = h*16+c, chk = 128+h*16+c;
        Kq[c*132+m] = (base[(size_t)chq*LSEQ+m0+m]-mu)*istd*gq_w[chq]+gq_b[chq];
        Kk[c*132+m] = (base[(size_t)chk*LSEQ+m0+m]-mu)*istd*gq_w[chk]+gq_b[chk];
    }
    __syncthreads();

    int i = tid>>4, j = tid&15;
    float q0=0,q1=0,q2=0,q3=0, k0=0,k1=0,k2=0,k3=0;
    for(int mm=0;mm<128;mm+=4){
        float4 qa = *(const float4*)&Kq[i*132+mm];
        float4 qb = *(const float4*)&Kq[j*132+mm];
        q0 += qa.x*qb.x; q1 += qa.y*qb.y; q2 += qa.z*qb.z; q3 += qa.w*qb.w;
        float4 ka = *(const float4*)&Kk[i*132+mm];
        float4 kb = *(const float4*)&Kk[j*132+mm];
        k0 += ka.x*kb.x; k1 += ka.y*kb.y; k2 += ka.z*kb.z; k3 += ka.w*kb.w;
    }
    atomicAdd(&covq[head*256 + i*16 + j], (q0+q1)+(q2+q3));
    atomicAdd(&covk[head*256 + i*16 + j], (k0+k1)+(k2+k3));

    if(i==0){
        float s=0.f;
        for(int mm=0;mm<128;mm+=4){
            float4 v = *(const float4*)&Kq[j*132+mm];
            s += (v.x+v.y)+(v.z+v.w);
        }
        atomicAdd(&sumq[head*16+j], s);
    }
    if(i==1){
        float s=0.f;
        for(int mm=0;mm<128;mm+=4){
            float4 v = *(const float4*)&Kk[j*132+mm];
            s += (v.x+v.y)+(v.z+v.w);
        }
        atomicAdd(&sumk[head*16+j], s);
    }
}

// ---------------------------------------------------------------------------
// Attention v7 = R9's v5 (128-row blocks, XCD swizzle — measured 49us) with
// head_fin folded into the prologue: each block recomputes its head's
// logit-LN istd from the covariances (~1us; removes a dispatch + gap).
// v6's 64-row blocks regressed (67us): per-block K/V staging sweep covers
// all 1024 m regardless of rows, so halving rows doubled staging work.
// ---------------------------------------------------------------------------
__global__ __launch_bounds__(256) void attn_kernel(
    const float* __restrict__ qkv,
    const float* __restrict__ s_qkv,
    const float* __restrict__ gq_w, const float* __restrict__ gq_b,
    const float* __restrict__ covq, const float* __restrict__ covk,
    const float* __restrict__ sumq, const float* __restrict__ sumk,
    float* __restrict__ out,
    float* __restrict__ out_stats)
{
    __shared__ short Qs[128*40];
    __shared__ short Ks[128*40];
    __shared__ short Vs[32*136];
    __shared__ short Ps[128*152];
    __shared__ float bounds_l[128];
    __shared__ float issum_l[128];
    __shared__ float sred4[4];

    int b = blockIdx.x;
    int head = b&63, rb = b>>6;     // XCD swizzle: all row-blocks of a head
    int n = head>>3, h = head&7;    // share an XCD -> K/V L2-resident (8.3MB
    int tid = threadIdx.x;          // fetch vs 65MB unswizzled, R9 vs R7)
    int wv = tid>>6, lane = tid&63;
    int col = lane&15, quad = lane>>4;
    int l0 = rb*128;

    // ---- head_fin fold: istd of the LxL logit map from covariances ----
    float ih;
    {
        float* fs = (float*)Ps;
        fs[tid] = covq[head*256+tid]*covk[head*256+tid];
        __syncthreads();
        for(int s=128;s>0;s>>=1){
            if(tid<s) fs[tid]+=fs[tid+s];
            __syncthreads();
        }
        if(tid==0){
            double S2 = (double)fs[0];
            double S1 = 0.0;
            for(int c=0;c<16;c++)
                S1 += (double)sumq[head*16+c]*(double)sumk[head*16+c];
            double cnt = 1048576.0;
            double mean = S1/cnt;
            double v2 = S2/cnt - mean*mean;
            if(v2 < 0.0) v2 = 0.0;
            fs[0] = (float)(1.0/sqrt(v2 + 1e-5));
        }
        __syncthreads();
        ih = fs[0];
        __syncthreads();
    }

    const float* base = qkv + (size_t)n*512*LSEQ;
    float s1 = s_qkv[2*n], s2v = s_qkv[2*n+1];
    float mu  = s1*(1.f/524288.f);
    float var = s2v*(1.f/524288.f) - mu*mu;
    float istd = rsqrtf(var + 1e-5f);

    {
        int row = tid>>1, hf = tid&1;
        uint4 z = {0,0,0,0};
        *(uint4*)&Qs[row*40 + 16 + hf*8] = z;
        *(uint4*)&Ks[row*40 + 16 + hf*8] = z;
    }

    {
        int row = tid>>1, cg = tid&1;
        float qn2p = 0.f;
        float qv[8];
        #pragma unroll
        for(int cc=0;cc<8;cc++){
            int ch = h*16 + cg*8 + cc;
            float w_ = gq_w[ch]*istd, b_ = gq_b[ch]-mu*istd*gq_w[ch];
            float x = base[(size_t)ch*LSEQ + l0 + row];
            float v = x*w_ + b_;
            qv[cc] = v;
            qn2p += v*v;
        }
        uint4 pq;
        pq.x = packbf(qv[0],qv[1]); pq.y = packbf(qv[2],qv[3]);
        pq.z = packbf(qv[4],qv[5]); pq.w = packbf(qv[6],qv[7]);
        *(uint4*)&Qs[row*40 + cg*8] = pq;
        float oth = __shfl_xor(qn2p, 1);
        if(cg==0) bounds_l[row] = sqrtf(qn2p + oth);
    }

    {
        float kn2max = 0.f;
        #pragma unroll
        for(int j=0;j<4;j++){
            int m = tid + j*256;
            float s = 0.f;
            for(int c=0;c<16;c++){
                int ch = 128+h*16+c;
                float x = base[(size_t)ch*LSEQ + m];
                float kv = (x-mu)*istd*gq_w[ch]+gq_b[ch];
                s += kv*kv;
            }
            kn2max = fmaxf(kn2max, s);
        }
        #pragma unroll
        for(int d=1;d<64;d<<=1) kn2max = fmaxf(kn2max, __shfl_xor(kn2max,d));
        if(lane==0) sred4[wv] = kn2max;
    }
    __syncthreads();
    float kmax = sqrtf(fmaxf(fmaxf(sred4[0],sred4[1]),fmaxf(sred4[2],sred4[3])));

    bf16x8 qf[2];
    float B2[2]; int grow[2];
    #pragma unroll
    for(int t=0;t<2;t++){
        int rl = (2*wv+t)*16 + col;
        qf[t] = *(bf16x8*)&Qs[rl*40 + quad*8];
        B2[t] = bounds_l[rl]*kmax*ih;
        grow[t] = l0 + rl;
    }

    int km_l = tid>>1, kg = tid&1;
    float kw8[8], kb8[8];
    #pragma unroll
    for(int cc=0;cc<8;cc++){
        int ch = 128+h*16+kg*8+cc;
        kw8[cc] = gq_w[ch]*istd;
        kb8[cc] = gq_b[ch]-mu*istd*gq_w[ch];
    }
    int vd = tid>>3, vmg = tid&7;
    float vw, vb;
    {
        int ch = 256+h*32+vd;
        vw = gq_w[ch]*istd;
        vb = gq_b[ch]-mu*istd*gq_w[ch];
    }
    const float* kp = base + (size_t)(128+h*16+kg*8)*LSEQ + km_l;
    const float* vp = base + (size_t)(256+h*32+vd)*LSEQ + vmg*16;

    f32x4 acc[2][2];
    #pragma unroll
    for(int t=0;t<2;t++){ acc[t][0]=(f32x4){0,0,0,0}; acc[t][1]=(f32x4){0,0,0,0}; }
    float ssum[2] = {0.f,0.f};
    const f32x4 zero4 = {0.f,0.f,0.f,0.f};

    for(int mc=0;mc<8;mc++){
        int M0 = mc*128;
        {
            float kv[8];
            #pragma unroll
            for(int cc=0;cc<8;cc++)
                kv[cc] = kp[(size_t)cc*LSEQ + M0]*kw8[cc] + kb8[cc];
            uint4 pk;
            pk.x=packbf(kv[0],kv[1]); pk.y=packbf(kv[2],kv[3]);
            pk.z=packbf(kv[4],kv[5]); pk.w=packbf(kv[6],kv[7]);
            *(uint4*)&Ks[km_l*40 + kg*8] = pk;
        }
        {
            float4 x0 = *(const float4*)&vp[M0];
            float4 x1 = *(const float4*)&vp[M0+4];
            float4 x2 = *(const float4*)&vp[M0+8];
            float4 x3 = *(const float4*)&vp[M0+12];
            uint4 p0, p1;
            p0.x = packbf(x0.x*vw+vb, x0.y*vw+vb);
            p0.y = packbf(x0.z*vw+vb, x0.w*vw+vb);
            p0.z = packbf(x1.x*vw+vb, x1.y*vw+vb);
            p0.w = packbf(x1.z*vw+vb, x1.w*vw+vb);
            p1.x = packbf(x2.x*vw+vb, x2.y*vw+vb);
            p1.y = packbf(x2.z*vw+vb, x2.w*vw+vb);
            p1.z = packbf(x3.x*vw+vb, x3.y*vw+vb);
            p1.w = packbf(x3.z*vw+vb, x3.w*vw+vb);
            *(uint4*)&Vs[vd*136 + vmg*16]     = p0;
            *(uint4*)&Vs[vd*136 + vmg*16 + 8] = p1;
        }
        __syncthreads();

        #pragma unroll
        for(int mt=0;mt<8;mt++){
            bf16x8 ak = *(bf16x8*)&Ks[(mt*16+col)*40 + quad*8];
            #pragma unroll
            for(int t=0;t<2;t++){
                f32x4 sc = __builtin_amdgcn_mfma_f32_16x16x32_bf16(ak, qf[t], zero4, 0,0,0);
                int mbase = M0 + mt*16 + quad*4;
                float pr[4];
                #pragma unroll
                for(int r=0;r<4;r++){
                    float e = __expf(fmaf(sc[r], ih, -B2[t]));
                    pr[r] = (mbase + r == grow[t]) ? 0.f : e;
                    ssum[t] += pr[r];
                }
                uint2 pw;
                pw.x = packbf(pr[0],pr[1]); pw.y = packbf(pr[2],pr[3]);
                *(uint2*)&Ps[((2*wv+t)*16+col)*152 + mt*16 + quad*4] = pw;
            }
        }
        #pragma unroll
        for(int kk=0;kk<4;kk++){
            bf16x8 bv0 = *(bf16x8*)&Vs[( col)*136 + kk*32 + quad*8];
            bf16x8 bv1 = *(bf16x8*)&Vs[((16+col))*136 + kk*32 + quad*8];
            #pragma unroll
            for(int t=0;t<2;t++){
                bf16x8 ap = *(bf16x8*)&Ps[((2*wv+t)*16+col)*152 + kk*32 + quad*8];
                acc[t][0] = __builtin_amdgcn_mfma_f32_16x16x32_bf16(ap, bv0, acc[t][0], 0,0,0);
                acc[t][1] = __builtin_amdgcn_mfma_f32_16x16x32_bf16(ap, bv1, acc[t][1], 0,0,0);
            }
        }
        __syncthreads();
    }

    #pragma unroll
    for(int t=0;t<2;t++){
        float v = ssum[t];
        v += __shfl_xor(v,16);
        v += __shfl_xor(v,32);
        if(quad==0) issum_l[(2*wv+t)*16+col] = v;
    }
    __syncthreads();
    if(tid<128) issum_l[tid] = 1.f/issum_l[tid];
    __syncthreads();

    float* ep = (float*)Ps;
    #pragma unroll
    for(int t=0;t<2;t++)
        #pragma unroll
        for(int dt=0;dt<2;dt++)
            *(f32x4*)&ep[(dt*16+col)*132 + (2*wv+t)*16 + quad*4] = acc[t][dt];
    __syncthreads();

    float lsum=0.f, lsq=0.f;
    size_t obase = (size_t)n*262144 + (size_t)h*32*LSEQ + l0;
    #pragma unroll
    for(int t=0;t<16;t++){
        int idx = t*256 + tid;
        int d = idx>>7, row = idx&127;
        float y = ep[d*132+row]*issum_l[row];
        out[obase + (size_t)d*LSEQ + row] = y;
        lsum += y; lsq += y*y;
    }
    float* red = (float*)Ks;
    red[tid]=lsum; red[256+tid]=lsq;
    __syncthreads();
    for(int s=128;s>0;s>>=1){
        if(tid<s){ red[tid]+=red[tid+s]; red[256+tid]+=red[256+tid+s]; }
        __syncthreads();
    }
    if(tid==0){
        atomicAdd(&out_stats[2*n],   red[0]);
        atomicAdd(&out_stats[2*n+1], red[256]);
    }
}

// ---------------------------------------------------------------------------
// ew_final: out = gelu( f1 + gn_g2(h2) ), f1 = gelu(f + gn_go(x)) recomputed.
// ---------------------------------------------------------------------------
__global__ __launch_bounds__(256) void ew_final(
    const float* __restrict__ f, const float* __restrict__ x,
    const float* __restrict__ h2,
    const float* __restrict__ sx, const float* __restrict__ sh,
    const float* __restrict__ go_w, const float* __restrict__ go_b,
    const float* __restrict__ g2_w, const float* __restrict__ g2_b,
    float* __restrict__ out)
{
    int idx = blockIdx.x*256 + threadIdx.x;
    int n = idx >> 16;
    int c = (idx >> 8) & 255;
    float mux, isx, muh, ish;
    {
        float s1 = sx[2*n], s2 = sx[2*n+1];
        mux = s1*(1.f/262144.f);
        isx = rsqrtf(s2*(1.f/262144.f) - mux*mux + 1e-5f);
        float t1 = sh[2*n], t2 = sh[2*n+1];
        muh = t1*(1.f/262144.f);
        ish = rsqrtf(t2*(1.f/262144.f) - muh*muh + 1e-5f);
    }
    float wo = go_w[c]*isx, bo = go_b[c]-mux*isx*go_w[c];
    float w2 = g2_w[c]*ish, b2 = g2_b[c]-muh*ish*g2_w[c];
    float4 xv = ((const float4*)x)[idx];
    float4 fv = ((const float4*)f)[idx];
    float4 hv = ((const float4*)h2)[idx];
    float4 ov;
    float f1;
    f1 = gelu_f(fv.x + xv.x*wo+bo); ov.x = gelu_f(f1 + hv.x*w2+b2);
    f1 = gelu_f(fv.y + xv.y*wo+bo); ov.y = gelu_f(f1 + hv.y*w2+b2);
    f1 = gelu_f(fv.z + xv.z*wo+bo); ov.z = gelu_f(f1 + hv.z*w2+b2);
    f1 = gelu_f(fv.w + xv.w*wo+bo); ov.w = gelu_f(f1 + hv.w*w2+b2);
    ((float4*)out)[idx] = ov;
}

// ---------------------------------------------------------------------------
extern "C" void kernel_launch(void* const* d_in, const int* in_sizes, int n_in,
                              void* d_out, int out_size, void* d_ws, size_t ws_size,
                              hipStream_t stream) {
    const float* f     = (const float*)d_in[0];
    const float* w_z   = (const float*)d_in[1];
    const float* gz_w  = (const float*)d_in[2];
    const float* gz_b  = (const float*)d_in[3];
    const float* w_qkv = (const float*)d_in[4];
    const float* gq_w  = (const float*)d_in[5];
    const float* gq_b  = (const float*)d_in[6];
    const float* w_out = (const float*)d_in[7];
    const float* go_w  = (const float*)d_in[8];
    const float* go_b  = (const float*)d_in[9];
    const float* w_f1  = (const float*)d_in[10];
    const float* g1_w  = (const float*)d_in[11];
    const float* g1_b  = (const float*)d_in[12];
    const float* w_f2  = (const float*)d_in[13];
    const float* g2_w  = (const float*)d_in[14];
    const float* g2_b  = (const float*)d_in[15];

    float* ws = (float*)d_ws;
    float* stats = ws;
    float* s_z    = stats + 0;
    float* s_qkv  = stats + 16;
    float* s_attn = stats + 32;
    float* s_x    = stats + 48;
    float* s_h1   = stats + 64;
    float* s_h2   = stats + 80;

    float* qkvF = ws + 256;            // 4M floats: qkv -> h1 -> h2
    float* z0F  = qkvF + 4194304;      // 2M floats: z0 -> attn_out -> t4(bf16)
    float* xF   = z0F + 2097152;       // 2M floats: covs -> x (persists)
    unsigned short* t0 = (unsigned short*)(xF + 2097152);  // t0 -> t2
    unsigned short* t1 = t0 + 2097152;                     // t1 -> t3
    unsigned short* wp = t1 + 2097152;
    unsigned short* t4 = (unsigned short*)z0F;
    unsigned short* wp_z   = wp;
    unsigned short* wp_qkv = wp + 65536;
    unsigned short* wp_out = wp + 196608;
    unsigned short* wp_f1  = wp + 262144;
    unsigned short* wp_f2  = wp + 393216;

    float* covq = xF;
    float* covk = xF + 16384;
    float* sumq = xF + 32768;
    float* sumk = xF + 33792;

    float* outp = (float*)d_out;

    dim3 blk(256);
    // prologue: pack weights + t0 xform + zero stats/covs (4 dispatches -> 1)
    prologue<<<1059,blk,0,stream>>>(w_z, w_qkv, w_out, w_f1, w_f2, wp,
        f, t0, stats, covq);
    // z0 = w_z @ t0
    gemm_bf16<<<dim3(16,4,8),blk,0,stream>>>(wp_z, t0, z0F, 256, 256, s_z);
    // t1 = bf16[gelu(gn_gz(z0))]
    xform_bf16<<<dim3(16,4,8),blk,0,stream>>>(z0F, nullptr, s_z, gz_w, gz_b,
        1.f/262144.f, 256, t1);
    // qkv = w_qkv @ t1
    gemm_bf16<<<dim3(16,8,8),blk,0,stream>>>(wp_qkv, t1, qkvF, 512, 256, s_qkv);
    // per-head covariances (head_fin folded into attn)
    head_cov<<<512,blk,0,stream>>>(qkvF, s_qkv, gq_w, gq_b, covq, covk, sumq, sumk);
    // attention -> attn_out (z0F region)
    attn_kernel<<<512,blk,0,stream>>>(qkvF, s_qkv, gq_w, gq_b,
        covq, covk, sumq, sumk, z0F, s_attn);
    // t2 = bf16[gelu(ln(attn_out))]
    xform_bf16<<<dim3(16,4,8),blk,0,stream>>>(z0F, nullptr, s_attn, nullptr, nullptr,
        1.f/262144.f, 256, t0);
    // x = w_out @ t2
    gemm_bf16<<<dim3(16,4,8),blk,0,stream>>>(wp_out, t0, xF, 256, 256, s_x);
    // t3 = bf16[gelu(f + gn_go(x))]
    xform_bf16<<<dim3(16,4,8),blk,0,stream>>>(xF, f, s_x, go_w, go_b,
        1.f/262144.f, 256, t1);
    // h1 = w_f1 @ t3
    gemm_bf16<<<dim3(16,8,8),blk,0,stream>>>(wp_f1, t1, qkvF, 512, 256, s_h1);
    // t4 = bf16[gelu(gn_g1(h1))]
    xform_bf16<<<dim3(16,8,8),blk,0,stream>>>(qkvF, nullptr, s_h1, g1_w, g1_b,
        1.f/524288.f, 512, t4);
    // h2 = w_f2 @ t4
    gemm_bf16<<<dim3(16,4,8),blk,0,stream>>>(wp_f2, t4, qkvF, 256, 512, s_h2);
    // out = gelu( gelu(f + gn_go(x)) + gn_g2(h2) )
    ew_final<<<2048,blk,0,stream>>>(f, xF, qkvF, s_x, s_h2,
        go_w, go_b, g2_w, g2_b, outp);
}